// Round 2
// baseline (194.998 us; speedup 1.0000x reference)
//
#include <hip/hip_runtime.h>
#include <hip/hip_bf16.h>
#include <cstdint>

// Problem constants (match reference)
#define Bn 8
#define Ln 4096
#define Dn 2048
#define Gn 32
#define GSn 64
static constexpr float EPS = 1e-5f;

// ---------------------------------------------------------------------------
// K1: per-(b,t,g) group means. One block per (b,t) row (D=2048 floats).
// 256 threads x 8 floats each; 8 threads per group of 64.
// ---------------------------------------------------------------------------
__global__ __launch_bounds__(256) void k_group_means(const float* __restrict__ x,
                                                     float* __restrict__ m) {
    const int row = blockIdx.x;          // b*L + t
    const int tid = threadIdx.x;
    const float4* xr = reinterpret_cast<const float4*>(x + (size_t)row * Dn) + tid * 2;
    float4 a = xr[0];
    float4 c = xr[1];
    float s = (a.x + a.y) + (a.z + a.w) + (c.x + c.y) + (c.z + c.w);
    // reduce across the 8 lanes that own this group (lanes are wave-contiguous)
    s += __shfl_xor(s, 1);
    s += __shfl_xor(s, 2);
    s += __shfl_xor(s, 4);
    if ((tid & 7) == 0) {
        const int g = tid >> 3;
        m[(size_t)row * Gn + g] = s * (1.0f / (float)GSn);
    }
}

// ---------------------------------------------------------------------------
// K2: per-(b,g) chain scan over L timesteps via prefix sums (closed-form
// Welford). One block (256 threads) per chain; 16 timesteps per thread.
// Emits mu[b,t,g], rstd[b,t,g], and the final count/mean/var outputs.
//
// NOTE: padding_mask (bool) and prev_count (int64 in source) are both pushed
// by the harness as int32 — read them as const int*. (Round-1 failure: mask
// read as bytes counted only every 4th element.)
// ---------------------------------------------------------------------------
__global__ __launch_bounds__(256) void k_scan(const float* __restrict__ m,
                                              const int* __restrict__ mask,
                                              const int* __restrict__ prev_count,
                                              const float* __restrict__ prev_mean,
                                              const float* __restrict__ prev_var,
                                              float* __restrict__ mu,
                                              float* __restrict__ rstd,
                                              float* __restrict__ out_count,
                                              float* __restrict__ out_mean,
                                              float* __restrict__ out_var) {
    const int bg = blockIdx.x;           // b*G + g
    const int b = bg / Gn;
    const int g = bg - b * Gn;
    const int tid = threadIdx.x;
    constexpr int TPT = Ln / 256;        // 16 timesteps per thread
    const int t0 = tid * TPT;

    float mv[TPT];
    float mk[TPT];
    float S = 0.f, Q = 0.f, P = 0.f;
    for (int i = 0; i < TPT; ++i) {
        const int t = t0 + i;
        const float v = m[((size_t)b * Ln + t) * Gn + g];
        const float k = mask[b * Ln + t] ? 1.f : 0.f;
        mv[i] = v;
        mk[i] = k;
        S += k * v;
        Q += k * v * v;
        P += k;
    }

    __shared__ float sS[256], sQ[256], sP[256];
    sS[tid] = S; sQ[tid] = Q; sP[tid] = P;
    __syncthreads();
    // Hillis-Steele inclusive scan over 256 thread partials
    for (int off = 1; off < 256; off <<= 1) {
        float aS = 0.f, aQ = 0.f, aP = 0.f;
        if (tid >= off) { aS = sS[tid - off]; aQ = sQ[tid - off]; aP = sP[tid - off]; }
        __syncthreads();
        sS[tid] += aS; sQ[tid] += aQ; sP[tid] += aP;
        __syncthreads();
    }
    const float eS = tid ? sS[tid - 1] : 0.f;
    const float eQ = tid ? sQ[tid - 1] : 0.f;
    const float eP = tid ? sP[tid - 1] : 0.f;

    const float c0  = (float)prev_count[b];
    const float mu0 = prev_mean[bg];
    const float v0  = prev_var[bg];
    const float A0  = c0 * mu0;
    const float M2b = v0 * fmaxf(c0, 1.f) + c0 * mu0 * mu0;

    float rS = eS, rQ = eQ, rP = eP;
    for (int i = 0; i < TPT; ++i) {
        rS += mk[i] * mv[i];
        rQ += mk[i] * mv[i] * mv[i];
        rP += mk[i];
        const float c  = c0 + rP;
        const float cs = fmaxf(c, 1.f);
        const float mean = (A0 + rS) / cs;
        const float var  = (M2b + rQ - cs * mean * mean) / cs;
        const size_t idx = ((size_t)b * Ln + (t0 + i)) * Gn + g;
        mu[idx]   = mean;
        rstd[idx] = rsqrtf(var + EPS);
        if (t0 + i == Ln - 1) {
            out_mean[bg] = mean;
            out_var[bg]  = var;
            if (g == 0) out_count[b] = c;   // harness reads flat f32
        }
    }
}

// ---------------------------------------------------------------------------
// K3: normalize + affine. One block per (b,t) row; 256 threads x 8 floats.
// ---------------------------------------------------------------------------
__global__ __launch_bounds__(256) void k_norm(const float* __restrict__ x,
                                              const float* __restrict__ mu,
                                              const float* __restrict__ rstd,
                                              const float* __restrict__ w,
                                              const float* __restrict__ bias,
                                              float* __restrict__ y) {
    const int row = blockIdx.x;          // b*L + t
    const int tid = threadIdx.x;
    const int g = tid >> 3;
    const size_t gi = (size_t)row * Gn + g;
    const float mean = mu[gi];
    const float rs   = rstd[gi];
    const float4* xr = reinterpret_cast<const float4*>(x + (size_t)row * Dn) + tid * 2;
    const float4* wr = reinterpret_cast<const float4*>(w) + tid * 2;
    const float4* br = reinterpret_cast<const float4*>(bias) + tid * 2;
    float4* yr = reinterpret_cast<float4*>(y + (size_t)row * Dn) + tid * 2;
#pragma unroll
    for (int i = 0; i < 2; ++i) {
        const float4 xv = xr[i];
        const float4 wv = wr[i];
        const float4 bv = br[i];
        float4 o;
        o.x = (xv.x - mean) * rs * wv.x + bv.x;
        o.y = (xv.y - mean) * rs * wv.y + bv.y;
        o.z = (xv.z - mean) * rs * wv.z + bv.z;
        o.w = (xv.w - mean) * rs * wv.w + bv.w;
        yr[i] = o;
    }
}

// ---------------------------------------------------------------------------
extern "C" void kernel_launch(void* const* d_in, const int* in_sizes, int n_in,
                              void* d_out, int out_size, void* d_ws, size_t ws_size,
                              hipStream_t stream) {
    (void)in_sizes; (void)n_in; (void)out_size; (void)ws_size;

    const float* x          = (const float*)d_in[0];
    const int*   mask       = (const int*)d_in[1];     // bool pushed as int32
    const int*   prev_count = (const int*)d_in[2];     // int pushed as int32
    const float* prev_mean  = (const float*)d_in[3];
    const float* prev_var   = (const float*)d_in[4];
    const float* weight     = (const float*)d_in[5];
    const float* bias       = (const float*)d_in[6];

    float* out = (float*)d_out;
    float* y         = out;                                   // B*L*D
    float* out_count = out + (size_t)Bn * Ln * Dn;            // B
    float* out_mean  = out_count + Bn;                        // B*G
    float* out_var   = out_mean + (size_t)Bn * Gn;            // B*G

    // workspace layout: m | mu | rstd, each B*L*G floats (4 MiB each)
    const size_t nBLG = (size_t)Bn * Ln * Gn;
    float* m    = (float*)d_ws;
    float* mu   = m + nBLG;
    float* rstd = mu + nBLG;

    const int rows = Bn * Ln;  // 32768
    k_group_means<<<rows, 256, 0, stream>>>(x, m);
    k_scan<<<Bn * Gn, 256, 0, stream>>>(m, mask, prev_count, prev_mean, prev_var,
                                        mu, rstd, out_count, out_mean, out_var);
    k_norm<<<rows, 256, 0, stream>>>(x, mu, rstd, weight, bias, y);
}